// Round 1
// baseline (11531.002 us; speedup 1.0000x reference)
//
#include <hip/hip_runtime.h>

// RNNSequenceEmbedder: B=64, T=256, V=32000, D=512, H=1024 (4H=4096)
// Inputs: tokens(i32 after harness cast), lengths(i32), embedding f32[V][D],
//         W_ih f32[4096][512], W_hh f32[4096][1024], b_ih[4096], b_hh[4096]
// Output: final h, f32 [64][1024]
//
// Design:
//  - bf16 MFMA (16x16x32) for both GEMMs, fp32 accumulation, fp32 cell state.
//  - k1_gemm precomputes Xg[t][b][4096] = x @ W_ih^T + (b_ih+b_hh)  (bf16).
//  - k2_lstm: persistent 256-WG kernel, W_hh resident in VGPRs (128/wave),
//    per-step hand-rolled grid barrier (threadfence + monotonic atomic ctr),
//    h broadcast through a ping-pong global bf16 buffer.

typedef __attribute__((ext_vector_type(8))) short  sh8;   // 8 x bf16 (4 VGPRs)
typedef __attribute__((ext_vector_type(4))) float  fx4;   // MFMA accumulator

__device__ __forceinline__ unsigned short f2bf(float x) {
  unsigned u = __builtin_bit_cast(unsigned, x);
  return (unsigned short)((u + 0x7FFFu + ((u >> 16) & 1u)) >> 16);  // RNE
}
__device__ __forceinline__ float bf2f(unsigned short s) {
  return __builtin_bit_cast(float, (unsigned)s << 16);
}
__device__ __forceinline__ float sigm(float x) { return 1.0f / (1.0f + __expf(-x)); }
__device__ __forceinline__ float tanh_(float x) { return 2.0f / (1.0f + __expf(-2.0f * x)) - 1.0f; }

// ---------------- prep kernels ----------------

__global__ void k_convert(const float* __restrict__ src, ushort* __restrict__ dst, int n4) {
  int i = blockIdx.x * blockDim.x + threadIdx.x;
  int stride = gridDim.x * blockDim.x;
  for (; i < n4; i += stride) {
    float4 v = ((const float4*)src)[i];
    ((ushort4*)dst)[i] = make_ushort4(f2bf(v.x), f2bf(v.y), f2bf(v.z), f2bf(v.w));
  }
}

__global__ void k_bias(const float* __restrict__ bi, const float* __restrict__ bh,
                       float* __restrict__ bias) {
  int i = blockIdx.x * 256 + threadIdx.x;
  if (i < 4096) bias[i] = bi[i] + bh[i];
}

// X[m][k] = embedding[tokens[b][t]][k], m = t*64 + b  (bf16)
__global__ void k_gather(const int* __restrict__ tokens, const float* __restrict__ emb,
                         ushort* __restrict__ X) {
  int m = blockIdx.x * 4 + (threadIdx.x >> 6);
  int lane = threadIdx.x & 63;
  int b = m & 63, tt = m >> 6;
  int tok = tokens[b * 256 + tt];
  const float4* src = (const float4*)(emb + (size_t)tok * 512);
  ushort4* dst = (ushort4*)(X + (size_t)m * 512);
#pragma unroll
  for (int i = 0; i < 2; ++i) {
    float4 v = src[lane + i * 64];
    dst[lane + i * 64] = make_ushort4(f2bf(v.x), f2bf(v.y), f2bf(v.z), f2bf(v.w));
  }
}

// ---------------- K1: Xg = X @ W_ih^T + bias ----------------
// M=16384 N=4096 K=512, 128x128 tile, BK=64, 4 waves (2x2 of 64x64).
// LDS tiles XOR-swizzled (byte ^= (row&7)<<4 within 128B rows) for
// conflict-free ds_read_b128 fragment loads.

__global__ __launch_bounds__(256) void k1_gemm(const ushort* __restrict__ X,
                                               const ushort* __restrict__ W,
                                               const float* __restrict__ bias,
                                               ushort* __restrict__ Xg) {
  __shared__ __align__(16) char As[128 * 128];  // 128 rows x 128B (64 bf16)
  __shared__ __align__(16) char Bs[128 * 128];
  const int tid = threadIdx.x, lane = tid & 63, wid = tid >> 6;
  const int wm = wid & 1, wn = wid >> 1;
  const int m0 = blockIdx.y * 128, n0 = blockIdx.x * 128;

  fx4 acc[4][4] = {};

  for (int kt = 0; kt < 8; ++kt) {
    if (kt) __syncthreads();
    // stage A,B tiles: per thread 4x16B each, linear global read, swizzled LDS write
#pragma unroll
    for (int i = 0; i < 4; ++i) {
      int a = tid * 16 + i * 4096;
      int row = a >> 7, inrow = a & 127;
      int dsa = (row << 7) + (inrow ^ ((row & 7) << 4));
      sh8 va = *(const sh8*)((const char*)X + (size_t)(m0 + row) * 1024 + kt * 128 + inrow);
      *(sh8*)(As + dsa) = va;
      sh8 vb = *(const sh8*)((const char*)W + (size_t)(n0 + row) * 1024 + kt * 128 + inrow);
      *(sh8*)(Bs + dsa) = vb;
    }
    __syncthreads();
#pragma unroll
    for (int kb = 0; kb < 2; ++kb) {
      sh8 af[4], bf[4];
      const int ko = kb * 64 + ((lane >> 4) << 4);
#pragma unroll
      for (int x = 0; x < 4; ++x) {
        int ar = wm * 64 + x * 16 + (lane & 15);
        af[x] = *(const sh8*)(As + (ar << 7) + (ko ^ ((ar & 7) << 4)));
        int br = wn * 64 + x * 16 + (lane & 15);
        bf[x] = *(const sh8*)(Bs + (br << 7) + (ko ^ ((br & 7) << 4)));
      }
#pragma unroll
      for (int mi = 0; mi < 4; ++mi)
#pragma unroll
        for (int ni = 0; ni < 4; ++ni)
          acc[mi][ni] = __builtin_amdgcn_mfma_f32_16x16x32_bf16(af[mi], bf[ni], acc[mi][ni], 0, 0, 0);
    }
  }
  // epilogue: C[m][n] with n = lane&15, m = (lane>>4)*4 + r  (verified C/D layout)
#pragma unroll
  for (int ni = 0; ni < 4; ++ni) {
    int n = n0 + wn * 64 + ni * 16 + (lane & 15);
    float bv = bias[n];
#pragma unroll
    for (int mi = 0; mi < 4; ++mi) {
#pragma unroll
      for (int r = 0; r < 4; ++r) {
        int m = m0 + wm * 64 + mi * 16 + ((lane >> 4) << 2) + r;
        Xg[(size_t)m * 4096 + n] = f2bf(acc[mi][ni][r] + bv);
      }
    }
  }
}

// ---------------- K2: persistent LSTM recurrence ----------------
// 256 WGs x 256 thr (1/CU; capacity >=2/CU so all resident -> barrier safe).
// WG (beta, hidx): batches [beta*32, beta*32+32), hidden units [hidx*8, hidx*8+8)
//   -> 32 gate columns {q*1024 + hidx*8 + j : q=0..3, j=0..7}.
// Waves 2x2 over (16 batch x 16 gatecol); each wave holds its W_hh B-fragments
// (16 cols x K=1024 bf16 = 128 VGPRs) for the entire kernel.

__global__ __launch_bounds__(256, 1) void k2_lstm(const ushort* __restrict__ Whh,
                                                  const ushort* __restrict__ Xg,
                                                  const int* __restrict__ lengths,
                                                  ushort* __restrict__ hbuf,
                                                  unsigned* __restrict__ ctr,
                                                  float* __restrict__ out) {
  __shared__ __align__(16) char hs_raw[32 * 1024];  // 32 batch rows x 512 k (bf16), per phase
  __shared__ float gs[32][33];                      // gate exchange (padded)
  __shared__ __align__(16) ushort hpack[32][8];     // h_new bf16 pack

  const int tid = threadIdx.x, lane = tid & 63, wid = tid >> 6;
  const int wg = blockIdx.x;
  const int hidx = wg & 127, beta = wg >> 7;
  const int wm = wid >> 1, wn = wid & 1;

  // ---- W_hh fragments resident in registers ----
  const int col_local = wn * 16 + (lane & 15);     // 0..31 within WG
  const int q = col_local >> 3, jj = col_local & 7;
  const int grow = q * 1024 + hidx * 8 + jj;       // global gate row
  sh8 wf[32];
  {
    const char* wsrc = (const char*)Whh + (size_t)grow * 2048 + ((lane >> 4) << 4);
#pragma unroll
    for (int kb = 0; kb < 32; ++kb) wf[kb] = *(const sh8*)(wsrc + (kb << 6));
  }

  const int b_loc = tid >> 3, j8 = tid & 7;
  const int bglob = beta * 32 + b_loc;
  const int len = lengths[bglob];
  float h_s = 0.0f, c_s = 0.0f;

  for (int t = 0; t < 256; ++t) {
    if (t > 0) {
      // grid barrier: release -> arrive -> spin -> acquire
      __threadfence();
      __syncthreads();
      if (tid == 0) {
        __hip_atomic_fetch_add(ctr, 1u, __ATOMIC_RELAXED, __HIP_MEMORY_SCOPE_AGENT);
        const unsigned target = 256u * (unsigned)t;
        while (__hip_atomic_load(ctr, __ATOMIC_RELAXED, __HIP_MEMORY_SCOPE_AGENT) < target)
          __builtin_amdgcn_s_sleep(1);
      }
      __syncthreads();
      __threadfence();
    }

    const char* hcur = (const char*)(hbuf + (size_t)(t & 1) * 65536) + (size_t)beta * 65536;
    fx4 acc = {0.f, 0.f, 0.f, 0.f};

#pragma unroll
    for (int p = 0; p < 2; ++p) {  // two k-halves (LDS = 32KB per phase)
      if (p) __syncthreads();
      // stage 32 rows x 1024B: linear global read, swizzled LDS write
#pragma unroll
      for (int i = 0; i < 8; ++i) {
        int a = tid * 16 + i * 4096;
        int row = a >> 10, inrow = a & 1023;
        sh8 v = *(const sh8*)(hcur + (size_t)row * 2048 + p * 1024 + inrow);
        *(sh8*)(hs_raw + (row << 10) + (inrow ^ ((row & 7) << 4))) = v;
      }
      __syncthreads();
      const int arow = wm * 16 + (lane & 15);
      const char* abase = hs_raw + (arow << 10);
      const int sw = (arow & 7) << 4;
#pragma unroll
      for (int kb2 = 0; kb2 < 16; ++kb2) {
        sh8 af = *(const sh8*)(abase + ((((kb2 << 6) + ((lane >> 4) << 4))) ^ sw));
        acc = __builtin_amdgcn_mfma_f32_16x16x32_bf16(af, wf[p * 16 + kb2], acc, 0, 0, 0);
      }
    }

    // exchange gates through LDS
    {
      const int gr = wm * 16 + ((lane >> 4) << 2);
      const int gc = wn * 16 + (lane & 15);
#pragma unroll
      for (int r = 0; r < 4; ++r) gs[gr + r][gc] = acc[r];
    }
    __syncthreads();

    // pointwise LSTM cell (fp32 state, masked by length)
    {
      const ushort* xrow = Xg + (size_t)t * 262144 + (size_t)bglob * 4096 + hidx * 8 + j8;
      float gi = gs[b_loc][ 0 + j8] + bf2f(xrow[0]);
      float gf = gs[b_loc][ 8 + j8] + bf2f(xrow[1024]);
      float gg = gs[b_loc][16 + j8] + bf2f(xrow[2048]);
      float go = gs[b_loc][24 + j8] + bf2f(xrow[3072]);
      if (t < len) {
        float iv = sigm(gi), fv = sigm(gf), gv = tanh_(gg), ov = sigm(go);
        c_s = fv * c_s + iv * gv;
        h_s = ov * tanh_(c_s);
      }
      hpack[b_loc][j8] = f2bf(h_s);
    }
    __syncthreads();
    if (tid < 32) {
      char* dst = (char*)(hbuf + (size_t)((t + 1) & 1) * 65536) +
                  (size_t)(beta * 32 + tid) * 2048 + hidx * 16;
      *(sh8*)dst = *(const sh8*)&hpack[tid][0];
    }
    // stores are ordered before the next barrier by __threadfence+__syncthreads
  }

  out[(size_t)bglob * 1024 + hidx * 8 + j8] = h_s;
}

// ---------------- launch ----------------

extern "C" void kernel_launch(void* const* d_in, const int* in_sizes, int n_in,
                              void* d_out, int out_size, void* d_ws, size_t ws_size,
                              hipStream_t stream) {
  (void)in_sizes; (void)n_in; (void)out_size;
  const int*   tokens  = (const int*)  d_in[0];
  const int*   lengths = (const int*)  d_in[1];
  const float* emb     = (const float*)d_in[2];
  const float* W_ih    = (const float*)d_in[3];
  const float* W_hh    = (const float*)d_in[4];
  const float* b_ih    = (const float*)d_in[5];
  const float* b_hh    = (const float*)d_in[6];
  float* out = (float*)d_out;
  char* ws = (char*)d_ws;

  const size_t off_X    = 0;                                    // 16 MiB
  const size_t off_Wih  = off_X    + (size_t)16384 * 512 * 2;   // 4 MiB
  const size_t off_Whh  = off_Wih  + (size_t)4096 * 512 * 2;    // 8 MiB
  const size_t off_bias = off_Whh  + (size_t)4096 * 1024 * 2;   // 16 KiB
  const size_t off_Xg   = off_bias + (size_t)4096 * 4;          // 128 MiB
  const size_t off_hbuf = off_Xg   + (size_t)16384 * 4096 * 2;  // 256 KiB
  const size_t off_ctr  = off_hbuf + (size_t)2 * 64 * 1024 * 2; // 64 B
  const size_t need     = off_ctr + 256;
  if (ws_size < need) return;  // ws too small -> visible absmax failure + ~0 dur

  ushort*   Xb    = (ushort*)(ws + off_X);
  ushort*   Wih_b = (ushort*)(ws + off_Wih);
  ushort*   Whh_b = (ushort*)(ws + off_Whh);
  float*    bias  = (float*) (ws + off_bias);
  ushort*   Xg    = (ushort*)(ws + off_Xg);
  ushort*   hb    = (ushort*)(ws + off_hbuf);
  unsigned* ctr   = (unsigned*)(ws + off_ctr);

  hipMemsetAsync(ws + off_hbuf, 0, (size_t)2 * 64 * 1024 * 2 + 256, stream);
  k_convert<<<1024, 256, 0, stream>>>(W_ih, Wih_b, 4096 * 512 / 4);
  k_convert<<<1024, 256, 0, stream>>>(W_hh, Whh_b, 4096 * 1024 / 4);
  k_bias<<<16, 256, 0, stream>>>(b_ih, b_hh, bias);
  k_gather<<<4096, 256, 0, stream>>>(tokens, emb, Xb);
  k1_gemm<<<dim3(32, 128), 256, 0, stream>>>(Xb, Wih_b, bias, Xg);
  k2_lstm<<<256, 256, 0, stream>>>(Whh_b, Xg, lengths, hb, ctr, out);
}

// Round 2
// 1499.087 us; speedup vs baseline: 7.6920x; 7.6920x over previous
//
#include <hip/hip_runtime.h>

// RNNSequenceEmbedder: B=64, T=256, V=32000, D=512, H=1024 (4H=4096)
// Output: final h, f32 [64][1024]
//
// R2: fence-free grid sync. h exchanged via coherent (sc0 sc1) stores/loads
// that complete at the shared coherence point; per-step per-half relaxed
// flag counters; NO __threadfence (no buffer_wbl2/buffer_inv L2 walks).

typedef __attribute__((ext_vector_type(8))) short  sh8;   // 8 x bf16 (4 VGPRs)
typedef __attribute__((ext_vector_type(4))) float  fx4;   // MFMA accumulator

__device__ __forceinline__ unsigned short f2bf(float x) {
  unsigned u = __builtin_bit_cast(unsigned, x);
  return (unsigned short)((u + 0x7FFFu + ((u >> 16) & 1u)) >> 16);  // RNE
}
__device__ __forceinline__ float bf2f(unsigned short s) {
  return __builtin_bit_cast(float, (unsigned)s << 16);
}
__device__ __forceinline__ float sigm(float x) { return 1.0f / (1.0f + __expf(-x)); }
__device__ __forceinline__ float tanh_(float x) { return 2.0f / (1.0f + __expf(-2.0f * x)) - 1.0f; }

// coherent 16B load/store: bypass L1+L2, complete at coherence point (IC)
__device__ __forceinline__ void ld_sc(sh8& v, const void* p) {
  asm volatile("global_load_dwordx4 %0, %1, off sc0 sc1" : "=v"(v) : "v"(p) : "memory");
}
__device__ __forceinline__ void st_sc(void* p, sh8 v) {
  asm volatile("global_store_dwordx4 %0, %1, off sc0 sc1" :: "v"(p), "v"(v) : "memory");
}

// ---------------- prep kernels ----------------

__global__ void k_convert(const float* __restrict__ src, ushort* __restrict__ dst, int n4) {
  int i = blockIdx.x * blockDim.x + threadIdx.x;
  int stride = gridDim.x * blockDim.x;
  for (; i < n4; i += stride) {
    float4 v = ((const float4*)src)[i];
    ((ushort4*)dst)[i] = make_ushort4(f2bf(v.x), f2bf(v.y), f2bf(v.z), f2bf(v.w));
  }
}

__global__ void k_bias(const float* __restrict__ bi, const float* __restrict__ bh,
                       float* __restrict__ bias) {
  int i = blockIdx.x * 256 + threadIdx.x;
  if (i < 4096) bias[i] = bi[i] + bh[i];
}

// X[m][k] = embedding[tokens[b][t]][k], m = t*64 + b  (bf16)
__global__ void k_gather(const int* __restrict__ tokens, const float* __restrict__ emb,
                         ushort* __restrict__ X) {
  int m = blockIdx.x * 4 + (threadIdx.x >> 6);
  int lane = threadIdx.x & 63;
  int b = m & 63, tt = m >> 6;
  int tok = tokens[b * 256 + tt];
  const float4* src = (const float4*)(emb + (size_t)tok * 512);
  ushort4* dst = (ushort4*)(X + (size_t)m * 512);
#pragma unroll
  for (int i = 0; i < 2; ++i) {
    float4 v = src[lane + i * 64];
    dst[lane + i * 64] = make_ushort4(f2bf(v.x), f2bf(v.y), f2bf(v.z), f2bf(v.w));
  }
}

// ---------------- K1: Xg = X @ W_ih^T + bias ----------------

__global__ __launch_bounds__(256) void k1_gemm(const ushort* __restrict__ X,
                                               const ushort* __restrict__ W,
                                               const float* __restrict__ bias,
                                               ushort* __restrict__ Xg) {
  __shared__ __align__(16) char As[128 * 128];
  __shared__ __align__(16) char Bs[128 * 128];
  const int tid = threadIdx.x, lane = tid & 63, wid = tid >> 6;
  const int wm = wid & 1, wn = wid >> 1;
  const int m0 = blockIdx.y * 128, n0 = blockIdx.x * 128;

  fx4 acc[4][4] = {};

  for (int kt = 0; kt < 8; ++kt) {
    if (kt) __syncthreads();
#pragma unroll
    for (int i = 0; i < 4; ++i) {
      int a = tid * 16 + i * 4096;
      int row = a >> 7, inrow = a & 127;
      int dsa = (row << 7) + (inrow ^ ((row & 7) << 4));
      sh8 va = *(const sh8*)((const char*)X + (size_t)(m0 + row) * 1024 + kt * 128 + inrow);
      *(sh8*)(As + dsa) = va;
      sh8 vb = *(const sh8*)((const char*)W + (size_t)(n0 + row) * 1024 + kt * 128 + inrow);
      *(sh8*)(Bs + dsa) = vb;
    }
    __syncthreads();
#pragma unroll
    for (int kb = 0; kb < 2; ++kb) {
      sh8 af[4], bf[4];
      const int ko = kb * 64 + ((lane >> 4) << 4);
#pragma unroll
      for (int x = 0; x < 4; ++x) {
        int ar = wm * 64 + x * 16 + (lane & 15);
        af[x] = *(const sh8*)(As + (ar << 7) + (ko ^ ((ar & 7) << 4)));
        int br = wn * 64 + x * 16 + (lane & 15);
        bf[x] = *(const sh8*)(Bs + (br << 7) + (ko ^ ((br & 7) << 4)));
      }
#pragma unroll
      for (int mi = 0; mi < 4; ++mi)
#pragma unroll
        for (int ni = 0; ni < 4; ++ni)
          acc[mi][ni] = __builtin_amdgcn_mfma_f32_16x16x32_bf16(af[mi], bf[ni], acc[mi][ni], 0, 0, 0);
    }
  }
#pragma unroll
  for (int ni = 0; ni < 4; ++ni) {
    int n = n0 + wn * 64 + ni * 16 + (lane & 15);
    float bv = bias[n];
#pragma unroll
    for (int mi = 0; mi < 4; ++mi) {
#pragma unroll
      for (int r = 0; r < 4; ++r) {
        int m = m0 + wm * 64 + mi * 16 + ((lane >> 4) << 2) + r;
        Xg[(size_t)m * 4096 + n] = f2bf(acc[mi][ni][r] + bv);
      }
    }
  }
}

// ---------------- K2: persistent LSTM recurrence ----------------
// 256 WGs x 256 thr (1 WG/CU, all resident). WG (beta, hidx): batches
// [beta*32, beta*32+32), hidden units [hidx*8, hidx*8+8) -> 32 gate cols.
// Sync: per-step per-half flag counter (relaxed agent atomics); h via
// sc0 sc1 stores/loads. No threadfence.

__global__ __launch_bounds__(256, 1) void k2_lstm(const ushort* __restrict__ Whh,
                                                  const ushort* __restrict__ Xg,
                                                  const int* __restrict__ lengths,
                                                  ushort* __restrict__ hbuf,
                                                  unsigned* __restrict__ flags,
                                                  float* __restrict__ out) {
  __shared__ __align__(16) char hs_raw[32 * 1024];  // 32 rows x 512 k (bf16) per phase
  __shared__ float gs[32][33];
  __shared__ __align__(16) ushort hpack[32][8];

  const int tid = threadIdx.x, lane = tid & 63, wid = tid >> 6;
  const int wg = blockIdx.x;
  const int hidx = wg & 127, beta = wg >> 7;
  const int wm = wid >> 1, wn = wid & 1;

  // W_hh fragments (compiler may keep in VGPR/AGPR or re-load from L1/L2)
  const int col_local = wn * 16 + (lane & 15);
  const int q = col_local >> 3, jj = col_local & 7;
  const int grow = q * 1024 + hidx * 8 + jj;
  sh8 wf[32];
  {
    const char* wsrc = (const char*)Whh + (size_t)grow * 2048 + ((lane >> 4) << 4);
#pragma unroll
    for (int kb = 0; kb < 32; ++kb) wf[kb] = *(const sh8*)(wsrc + (kb << 6));
  }

  const int b_loc = tid >> 3, j8 = tid & 7;
  const int bglob = beta * 32 + b_loc;
  const int len = lengths[bglob];
  float h_s = 0.0f, c_s = 0.0f;

  // A-fragment LDS addressing (constant across steps)
  const int arow = wm * 16 + (lane & 15);
  const int asw = (arow & 7) << 4;
  const char* abase = hs_raw + (arow << 10);
  const int ahi = (lane >> 4) << 4;

  for (int t = 0; t < 256; ++t) {
    // prefetch Xg for this step (independent of h)
    const ushort* xrow = Xg + (size_t)t * 262144 + (size_t)bglob * 4096 + hidx * 8 + j8;
    float xg0 = bf2f(xrow[0]);
    float xg1 = bf2f(xrow[1024]);
    float xg2 = bf2f(xrow[2048]);
    float xg3 = bf2f(xrow[3072]);

    if (t > 0) {
      if (tid == 0) {
        const unsigned* fl = flags + 2 * (t - 1) + beta;
        while (__hip_atomic_load(fl, __ATOMIC_RELAXED, __HIP_MEMORY_SCOPE_AGENT) < 128u) {}
      }
      __syncthreads();
    }

    const char* hbase = (const char*)hbuf + (size_t)(t & 1) * 131072 + (size_t)beta * 65536;
    fx4 acc0 = {0.f, 0.f, 0.f, 0.f}, acc1 = {0.f, 0.f, 0.f, 0.f};

    // ---- phase 0: stage k[0..512) ----
    sh8 t0[8];
#pragma unroll
    for (int i = 0; i < 8; ++i) {
      int a = tid * 16 + i * 4096;
      ld_sc(t0[i], hbase + ((a >> 10) << 11) + (a & 1023));
    }
    asm volatile("s_waitcnt vmcnt(0)" ::: "memory");
    __builtin_amdgcn_sched_barrier(0);
#pragma unroll
    for (int i = 0; i < 8; ++i) {
      int a = tid * 16 + i * 4096;
      int row = a >> 10, inrow = a & 1023;
      *(sh8*)(hs_raw + (row << 10) + (inrow ^ ((row & 7) << 4))) = t0[i];
    }
    __syncthreads();

    // issue phase-1 loads (k[512..1024)) under phase-0 MFMA
    sh8 t1[8];
#pragma unroll
    for (int i = 0; i < 8; ++i) {
      int a = tid * 16 + i * 4096;
      ld_sc(t1[i], hbase + ((a >> 10) << 11) + 1024 + (a & 1023));
    }

    // ---- MFMA phase 0 ----
#pragma unroll
    for (int kb = 0; kb < 8; ++kb) {
      sh8 af = *(const sh8*)(abase + (((kb << 6) + ahi) ^ asw));
      acc0 = __builtin_amdgcn_mfma_f32_16x16x32_bf16(af, wf[kb], acc0, 0, 0, 0);
    }
#pragma unroll
    for (int kb = 8; kb < 16; ++kb) {
      sh8 af = *(const sh8*)(abase + (((kb << 6) + ahi) ^ asw));
      acc1 = __builtin_amdgcn_mfma_f32_16x16x32_bf16(af, wf[kb], acc1, 0, 0, 0);
    }

    asm volatile("s_waitcnt vmcnt(0)" ::: "memory");
    __builtin_amdgcn_sched_barrier(0);
    __syncthreads();  // all waves done reading phase 0
#pragma unroll
    for (int i = 0; i < 8; ++i) {
      int a = tid * 16 + i * 4096;
      int row = a >> 10, inrow = a & 1023;
      *(sh8*)(hs_raw + (row << 10) + (inrow ^ ((row & 7) << 4))) = t1[i];
    }
    __syncthreads();

    // ---- MFMA phase 1 ----
#pragma unroll
    for (int kb = 0; kb < 8; ++kb) {
      sh8 af = *(const sh8*)(abase + (((kb << 6) + ahi) ^ asw));
      acc0 = __builtin_amdgcn_mfma_f32_16x16x32_bf16(af, wf[16 + kb], acc0, 0, 0, 0);
    }
#pragma unroll
    for (int kb = 8; kb < 16; ++kb) {
      sh8 af = *(const sh8*)(abase + (((kb << 6) + ahi) ^ asw));
      acc1 = __builtin_amdgcn_mfma_f32_16x16x32_bf16(af, wf[16 + kb], acc1, 0, 0, 0);
    }

    // exchange gates through LDS
    {
      const int gr = wm * 16 + ((lane >> 4) << 2);
      const int gc = wn * 16 + (lane & 15);
#pragma unroll
      for (int r = 0; r < 4; ++r) gs[gr + r][gc] = acc0[r] + acc1[r];
    }
    __syncthreads();

    // pointwise LSTM cell
    {
      float gi = gs[b_loc][ 0 + j8] + xg0;
      float gf = gs[b_loc][ 8 + j8] + xg1;
      float gg = gs[b_loc][16 + j8] + xg2;
      float go = gs[b_loc][24 + j8] + xg3;
      if (t < len) {
        float iv = sigm(gi), fv = sigm(gf), gv = tanh_(gg), ov = sigm(go);
        c_s = fv * c_s + iv * gv;
        h_s = ov * tanh_(c_s);
      }
      hpack[b_loc][j8] = f2bf(h_s);
    }
    __syncthreads();

    // publish h_{t+1}: coherent store -> vmcnt(0) -> relaxed flag inc
    if (tid < 32) {
      char* dst = (char*)hbuf + (size_t)((t + 1) & 1) * 131072 +
                  (size_t)(beta * 32 + tid) * 2048 + hidx * 16;
      st_sc(dst, *(const sh8*)&hpack[tid][0]);
    }
    if (tid == 0) {
      asm volatile("s_waitcnt vmcnt(0)" ::: "memory");
      __hip_atomic_fetch_add(flags + 2 * t + beta, 1u, __ATOMIC_RELAXED, __HIP_MEMORY_SCOPE_AGENT);
    }
  }

  out[(size_t)bglob * 1024 + hidx * 8 + j8] = h_s;
}

// ---------------- launch ----------------

extern "C" void kernel_launch(void* const* d_in, const int* in_sizes, int n_in,
                              void* d_out, int out_size, void* d_ws, size_t ws_size,
                              hipStream_t stream) {
  (void)in_sizes; (void)n_in; (void)out_size;
  const int*   tokens  = (const int*)  d_in[0];
  const int*   lengths = (const int*)  d_in[1];
  const float* emb     = (const float*)d_in[2];
  const float* W_ih    = (const float*)d_in[3];
  const float* W_hh    = (const float*)d_in[4];
  const float* b_ih    = (const float*)d_in[5];
  const float* b_hh    = (const float*)d_in[6];
  float* out = (float*)d_out;
  char* ws = (char*)d_ws;

  const size_t off_X    = 0;                                    // 16 MiB
  const size_t off_Wih  = off_X    + (size_t)16384 * 512 * 2;   // 4 MiB
  const size_t off_Whh  = off_Wih  + (size_t)4096 * 512 * 2;    // 8 MiB
  const size_t off_bias = off_Whh  + (size_t)4096 * 1024 * 2;   // 16 KiB
  const size_t off_Xg   = off_bias + (size_t)4096 * 4;          // 128 MiB
  const size_t off_hbuf = off_Xg   + (size_t)16384 * 4096 * 2;  // 256 KiB
  const size_t off_flag = off_hbuf + (size_t)2 * 64 * 1024 * 2; // 2 KiB
  const size_t need     = off_flag + 4096;
  if (ws_size < need) return;

  ushort*   Xb    = (ushort*)(ws + off_X);
  ushort*   Wih_b = (ushort*)(ws + off_Wih);
  ushort*   Whh_b = (ushort*)(ws + off_Whh);
  float*    bias  = (float*) (ws + off_bias);
  ushort*   Xg    = (ushort*)(ws + off_Xg);
  ushort*   hb    = (ushort*)(ws + off_hbuf);
  unsigned* flags = (unsigned*)(ws + off_flag);

  hipMemsetAsync(ws + off_hbuf, 0, (size_t)2 * 64 * 1024 * 2 + 4096, stream);
  k_convert<<<1024, 256, 0, stream>>>(W_ih, Wih_b, 4096 * 512 / 4);
  k_convert<<<1024, 256, 0, stream>>>(W_hh, Whh_b, 4096 * 1024 / 4);
  k_bias<<<16, 256, 0, stream>>>(b_ih, b_hh, bias);
  k_gather<<<4096, 256, 0, stream>>>(tokens, emb, Xb);
  k1_gemm<<<dim3(32, 128), 256, 0, stream>>>(Xb, Wih_b, bias, Xg);
  k2_lstm<<<256, 256, 0, stream>>>(Whh_b, Xg, lengths, hb, flags, out);
}

// Round 4
// 1078.967 us; speedup vs baseline: 10.6871x; 1.3894x over previous
//
#include <hip/hip_runtime.h>

// RNNSequenceEmbedder: B=64, T=256, V=32000, D=512, H=1024 (4H=4096)
// Output: final h, f32 [64][1024]
//
// R3 (resubmit; prior round hit GPU acquisition timeout): quarter-batch
// sharding (WG = 16 batches x 16 hidden units), wf pinned in VGPRs,
// single-phase 32KB h staging, per-wave seqno flags (no atomics),
// per-thread 2B coherent h stores. 2-3 syncthreads/step.

typedef __attribute__((ext_vector_type(8))) short    sh8;  // 8 x bf16
typedef __attribute__((ext_vector_type(4))) float    fx4;  // MFMA acc
typedef __attribute__((ext_vector_type(4))) unsigned ux4;

__device__ __forceinline__ unsigned short f2bf(float x) {
  unsigned u = __builtin_bit_cast(unsigned, x);
  return (unsigned short)((u + 0x7FFFu + ((u >> 16) & 1u)) >> 16);  // RNE
}
__device__ __forceinline__ float bf2f(unsigned short s) {
  return __builtin_bit_cast(float, (unsigned)s << 16);
}
__device__ __forceinline__ float sigm(float x) { return 1.0f / (1.0f + __expf(-x)); }
__device__ __forceinline__ float tanh_(float x) { return 2.0f / (1.0f + __expf(-2.0f * x)) - 1.0f; }

// coherent ops: complete at device coherence point (bypass L1/L2)
__device__ __forceinline__ void ld_sc(sh8& v, const void* p) {
  asm volatile("global_load_dwordx4 %0, %1, off sc0 sc1" : "=v"(v) : "v"(p) : "memory");
}
__device__ __forceinline__ void ld_sc4u(ux4& v, const void* p) {
  asm volatile("global_load_dwordx4 %0, %1, off sc0 sc1" : "=v"(v) : "v"(p) : "memory");
}
__device__ __forceinline__ void st_sc2(void* p, unsigned v) {
  asm volatile("global_store_short %0, %1, off sc0 sc1" :: "v"(p), "v"(v) : "memory");
}
__device__ __forceinline__ void st_sc4(void* p, unsigned v) {
  asm volatile("global_store_dword %0, %1, off sc0 sc1" :: "v"(p), "v"(v) : "memory");
}

// ---------------- prep kernels ----------------

__global__ void k_convert(const float* __restrict__ src, ushort* __restrict__ dst, int n4) {
  int i = blockIdx.x * blockDim.x + threadIdx.x;
  int stride = gridDim.x * blockDim.x;
  for (; i < n4; i += stride) {
    float4 v = ((const float4*)src)[i];
    ((ushort4*)dst)[i] = make_ushort4(f2bf(v.x), f2bf(v.y), f2bf(v.z), f2bf(v.w));
  }
}

__global__ void k_bias(const float* __restrict__ bi, const float* __restrict__ bh,
                       float* __restrict__ bias) {
  int i = blockIdx.x * 256 + threadIdx.x;
  if (i < 4096) bias[i] = bi[i] + bh[i];
}

__global__ void k_gather(const int* __restrict__ tokens, const float* __restrict__ emb,
                         ushort* __restrict__ X) {
  int m = blockIdx.x * 4 + (threadIdx.x >> 6);
  int lane = threadIdx.x & 63;
  int b = m & 63, tt = m >> 6;
  int tok = tokens[b * 256 + tt];
  const float4* src = (const float4*)(emb + (size_t)tok * 512);
  ushort4* dst = (ushort4*)(X + (size_t)m * 512);
#pragma unroll
  for (int i = 0; i < 2; ++i) {
    float4 v = src[lane + i * 64];
    dst[lane + i * 64] = make_ushort4(f2bf(v.x), f2bf(v.y), f2bf(v.z), f2bf(v.w));
  }
}

// ---------------- K1: Xg = X @ W_ih^T + bias ----------------

__global__ __launch_bounds__(256) void k1_gemm(const ushort* __restrict__ X,
                                               const ushort* __restrict__ W,
                                               const float* __restrict__ bias,
                                               ushort* __restrict__ Xg) {
  __shared__ __align__(16) char As[128 * 128];
  __shared__ __align__(16) char Bs[128 * 128];
  const int tid = threadIdx.x, lane = tid & 63, wid = tid >> 6;
  const int wm = wid & 1, wn = wid >> 1;
  const int m0 = blockIdx.y * 128, n0 = blockIdx.x * 128;

  fx4 acc[4][4] = {};

  for (int kt = 0; kt < 8; ++kt) {
    if (kt) __syncthreads();
#pragma unroll
    for (int i = 0; i < 4; ++i) {
      int a = tid * 16 + i * 4096;
      int row = a >> 7, inrow = a & 127;
      int dsa = (row << 7) + (inrow ^ ((row & 7) << 4));
      sh8 va = *(const sh8*)((const char*)X + (size_t)(m0 + row) * 1024 + kt * 128 + inrow);
      *(sh8*)(As + dsa) = va;
      sh8 vb = *(const sh8*)((const char*)W + (size_t)(n0 + row) * 1024 + kt * 128 + inrow);
      *(sh8*)(Bs + dsa) = vb;
    }
    __syncthreads();
#pragma unroll
    for (int kb = 0; kb < 2; ++kb) {
      sh8 af[4], bf[4];
      const int ko = kb * 64 + ((lane >> 4) << 4);
#pragma unroll
      for (int x = 0; x < 4; ++x) {
        int ar = wm * 64 + x * 16 + (lane & 15);
        af[x] = *(const sh8*)(As + (ar << 7) + (ko ^ ((ar & 7) << 4)));
        int br = wn * 64 + x * 16 + (lane & 15);
        bf[x] = *(const sh8*)(Bs + (br << 7) + (ko ^ ((br & 7) << 4)));
      }
#pragma unroll
      for (int mi = 0; mi < 4; ++mi)
#pragma unroll
        for (int ni = 0; ni < 4; ++ni)
          acc[mi][ni] = __builtin_amdgcn_mfma_f32_16x16x32_bf16(af[mi], bf[ni], acc[mi][ni], 0, 0, 0);
    }
  }
#pragma unroll
  for (int ni = 0; ni < 4; ++ni) {
    int n = n0 + wn * 64 + ni * 16 + (lane & 15);
    float bv = bias[n];
#pragma unroll
    for (int mi = 0; mi < 4; ++mi) {
#pragma unroll
      for (int r = 0; r < 4; ++r) {
        int m = m0 + wm * 64 + mi * 16 + ((lane >> 4) << 2) + r;
        Xg[(size_t)m * 4096 + n] = f2bf(acc[mi][ni][r] + bv);
      }
    }
  }
}

// ---------------- K2: persistent LSTM recurrence ----------------
// Grid 256 = 64 hidx x 4 beta (batch quarter). WG: batches [beta*16,+16),
// hidden units [hidx*16,+16). Wave wn == gate wn (i/f/g/o), 16 cols each.
// wf (W_hh B-fragments, 128 VGPR) pinned. Flags: per (wg,wave) seqno.

__global__ __launch_bounds__(256, 1) void k2_lstm(const ushort* __restrict__ Whh,
                                                  const ushort* __restrict__ Xg,
                                                  const int* __restrict__ lengths,
                                                  ushort* __restrict__ hbuf,
                                                  unsigned* __restrict__ flags,
                                                  float* __restrict__ out) {
  __shared__ __align__(16) char hs[32768];   // 16 rows x 2048B (swizzled)
  __shared__ float gs[16][65];               // gates exchange

  const int tid = threadIdx.x, lane = tid & 63, wn = tid >> 6;
  const int wg = blockIdx.x;
  const int hidx = wg & 63, beta = wg >> 6;

  // ---- W_hh fragments resident in registers (pinned) ----
  const int grow = wn * 1024 + hidx * 16 + (lane & 15);  // gate row
  sh8 wf[32];
  {
    const char* wsrc = (const char*)Whh + (size_t)grow * 2048 + ((lane >> 4) << 4);
#pragma unroll
    for (int kb = 0; kb < 32; ++kb) {
      wf[kb] = *(const sh8*)(wsrc + (kb << 6));
      asm volatile("" : "+v"(wf[kb]));  // opaque def: no rematerialization
    }
  }

  const int b_loc = tid >> 4, j16 = tid & 15;
  const int bglob = beta * 16 + b_loc;
  const int len = lengths[bglob];
  float h_s = 0.0f, c_s = 0.0f;

  // A-fragment LDS addressing (constant across steps)
  const int arow = lane & 15;
  const char* abase = hs + (arow << 11);
  const int asw = (arow & 7) << 4;
  const int ahi = (lane >> 4) << 4;

  // Xg for t=0 (prefetched; raw ushorts, converted at use)
  const ushort* x0 = Xg + (size_t)bglob * 4096 + hidx * 16 + j16;
  ushort xcu0 = x0[0], xcu1 = x0[1024], xcu2 = x0[2048], xcu3 = x0[3072];

  unsigned* const myflag = flags + beta * 256 + hidx * 4 + wn;
  const char* const fpoll = (const char*)(flags + beta * 256) + lane * 16;

  for (int t = 0; t < 256; ++t) {
    if (t > 0) {
      if (wn == 0) {
        const unsigned tgt = (unsigned)t;
        for (;;) {
          ux4 f;
          ld_sc4u(f, fpoll);
          asm volatile("s_waitcnt vmcnt(0)" ::: "memory");
          unsigned m01 = f[0] < f[1] ? f[0] : f[1];
          unsigned m23 = f[2] < f[3] ? f[2] : f[3];
          unsigned m = m01 < m23 ? m01 : m23;
          if (__all(m >= tgt)) break;
        }
      }
      __syncthreads();
    }

    // ---- stage h quarter (16 rows x 2KB) : coherent loads -> swizzled LDS ----
    const char* hbase = (const char*)hbuf + (size_t)(t & 1) * 131072 + (size_t)beta * 32768;
    sh8 st[8];
#pragma unroll
    for (int i = 0; i < 8; ++i) ld_sc(st[i], hbase + tid * 16 + i * 4096);
    asm volatile("s_waitcnt vmcnt(0)" ::: "memory");
    __builtin_amdgcn_sched_barrier(0);
#pragma unroll
    for (int i = 0; i < 8; ++i) {
      int a = tid * 16 + i * 4096;
      int row = a >> 11, inrow = a & 2047;
      *(sh8*)(hs + (row << 11) + (inrow ^ ((row & 7) << 4))) = st[i];
    }
    __syncthreads();

    // prefetch next step's Xg (consumed next iteration; full-step latency window)
    const int tn = (t + 1) & 255;
    const ushort* xn = Xg + (size_t)tn * 262144 + (size_t)bglob * 4096 + hidx * 16 + j16;
    ushort nx0 = xn[0], nx1 = xn[1024], nx2 = xn[2048], nx3 = xn[3072];

    // ---- MFMA: 16 batches x 16 gate-cols, K=1024, 4 acc chains ----
    fx4 ac0 = {0,0,0,0}, ac1 = {0,0,0,0}, ac2 = {0,0,0,0}, ac3 = {0,0,0,0};
#pragma unroll
    for (int kb = 0; kb < 8; ++kb) {
      sh8 a0 = *(const sh8*)(abase + ((((4*kb+0) << 6) + ahi) ^ asw));
      ac0 = __builtin_amdgcn_mfma_f32_16x16x32_bf16(a0, wf[4*kb+0], ac0, 0, 0, 0);
      sh8 a1 = *(const sh8*)(abase + ((((4*kb+1) << 6) + ahi) ^ asw));
      ac1 = __builtin_amdgcn_mfma_f32_16x16x32_bf16(a1, wf[4*kb+1], ac1, 0, 0, 0);
      sh8 a2 = *(const sh8*)(abase + ((((4*kb+2) << 6) + ahi) ^ asw));
      ac2 = __builtin_amdgcn_mfma_f32_16x16x32_bf16(a2, wf[4*kb+2], ac2, 0, 0, 0);
      sh8 a3 = *(const sh8*)(abase + ((((4*kb+3) << 6) + ahi) ^ asw));
      ac3 = __builtin_amdgcn_mfma_f32_16x16x32_bf16(a3, wf[4*kb+3], ac3, 0, 0, 0);
    }
    fx4 acc = (ac0 + ac1) + (ac2 + ac3);

    // ---- gate exchange ----
    {
      const int gr = (lane >> 4) << 2;
      const int gc = wn * 16 + (lane & 15);
#pragma unroll
      for (int r = 0; r < 4; ++r) gs[gr + r][gc] = acc[r];
    }
    __syncthreads();

    // ---- pointwise LSTM cell ----
    {
      float gi = gs[b_loc][ 0 + j16] + bf2f(xcu0);
      float gf = gs[b_loc][16 + j16] + bf2f(xcu1);
      float gg = gs[b_loc][32 + j16] + bf2f(xcu2);
      float go = gs[b_loc][48 + j16] + bf2f(xcu3);
      if (t < len) {
        float iv = sigm(gi), fv = sigm(gf), gv = tanh_(gg), ov = sigm(go);
        c_s = fv * c_s + iv * gv;
        h_s = ov * tanh_(c_s);
      }
    }

    // ---- publish h_{t+1}: per-thread 2B coherent store -> per-wave flag ----
    {
      char* dst = (char*)hbuf + (size_t)((t + 1) & 1) * 131072 +
                  (size_t)bglob * 2048 + (size_t)(hidx * 16 + j16) * 2;
      st_sc2(dst, (unsigned)f2bf(h_s));
    }
    asm volatile("s_waitcnt vmcnt(0)" ::: "memory");
    if (lane == 0) st_sc4(myflag, (unsigned)(t + 1));

    xcu0 = nx0; xcu1 = nx1; xcu2 = nx2; xcu3 = nx3;
  }

  out[(size_t)bglob * 1024 + hidx * 16 + j16] = h_s;
}

// ---------------- launch ----------------

extern "C" void kernel_launch(void* const* d_in, const int* in_sizes, int n_in,
                              void* d_out, int out_size, void* d_ws, size_t ws_size,
                              hipStream_t stream) {
  (void)in_sizes; (void)n_in; (void)out_size;
  const int*   tokens  = (const int*)  d_in[0];
  const int*   lengths = (const int*)  d_in[1];
  const float* emb     = (const float*)d_in[2];
  const float* W_ih    = (const float*)d_in[3];
  const float* W_hh    = (const float*)d_in[4];
  const float* b_ih    = (const float*)d_in[5];
  const float* b_hh    = (const float*)d_in[6];
  float* out = (float*)d_out;
  char* ws = (char*)d_ws;

  const size_t off_X    = 0;                                    // 16 MiB
  const size_t off_Wih  = off_X    + (size_t)16384 * 512 * 2;   // 4 MiB
  const size_t off_Whh  = off_Wih  + (size_t)4096 * 512 * 2;    // 8 MiB
  const size_t off_bias = off_Whh  + (size_t)4096 * 1024 * 2;   // 16 KiB
  const size_t off_Xg   = off_bias + (size_t)4096 * 4;          // 128 MiB
  const size_t off_hbuf = off_Xg   + (size_t)16384 * 4096 * 2;  // 256 KiB
  const size_t off_flag = off_hbuf + (size_t)2 * 64 * 1024 * 2; // 4 KiB
  const size_t need     = off_flag + 4096;
  if (ws_size < need) return;

  ushort*   Xb    = (ushort*)(ws + off_X);
  ushort*   Wih_b = (ushort*)(ws + off_Wih);
  ushort*   Whh_b = (ushort*)(ws + off_Whh);
  float*    bias  = (float*) (ws + off_bias);
  ushort*   Xg    = (ushort*)(ws + off_Xg);
  ushort*   hb    = (ushort*)(ws + off_hbuf);
  unsigned* flags = (unsigned*)(ws + off_flag);

  hipMemsetAsync(ws + off_hbuf, 0, (size_t)2 * 64 * 1024 * 2 + 4096, stream);
  k_convert<<<1024, 256, 0, stream>>>(W_ih, Wih_b, 4096 * 512 / 4);
  k_convert<<<1024, 256, 0, stream>>>(W_hh, Whh_b, 4096 * 1024 / 4);
  k_bias<<<16, 256, 0, stream>>>(b_ih, b_hh, bias);
  k_gather<<<4096, 256, 0, stream>>>(tokens, emb, Xb);
  k1_gemm<<<dim3(32, 128), 256, 0, stream>>>(Xb, Wih_b, bias, Xg);
  k2_lstm<<<256, 256, 0, stream>>>(Whh_b, Xg, lengths, hb, flags, out);
}

// Round 5
// 886.191 us; speedup vs baseline: 13.0119x; 1.2175x over previous
//
#include <hip/hip_runtime.h>

// RNNSequenceEmbedder: B=64, T=256, V=32000, D=512, H=1024 (4H=4096)
// Output: final h, f32 [64][1024]
//
// R5: self-validating tagged h-exchange. Each h unit is a dword
// (bf16<<16 | step_tag); consumer staging loads ARE the arrival poll
// (re-issue until all 64 embedded tags match). No flags, no producer
// vmcnt-before-flag, no separate staging read: ~3 IC round trips -> ~1.
// Dword atomicity makes this correct under any XCD mapping.

typedef __attribute__((ext_vector_type(8))) short    sh8;  // 8 x bf16
typedef __attribute__((ext_vector_type(4))) float    fx4;  // MFMA acc
typedef __attribute__((ext_vector_type(4))) unsigned ux4;
typedef __attribute__((ext_vector_type(2))) unsigned ux2;

__device__ __forceinline__ unsigned short f2bf(float x) {
  unsigned u = __builtin_bit_cast(unsigned, x);
  return (unsigned short)((u + 0x7FFFu + ((u >> 16) & 1u)) >> 16);  // RNE
}
__device__ __forceinline__ float bf2f(unsigned short s) {
  return __builtin_bit_cast(float, (unsigned)s << 16);
}
__device__ __forceinline__ float sigm(float x) { return 1.0f / (1.0f + __expf(-x)); }
__device__ __forceinline__ float tanh_(float x) { return 2.0f / (1.0f + __expf(-2.0f * x)) - 1.0f; }

// coherent ops: bypass L1/L2, complete at device coherence point (IC)
__device__ __forceinline__ void ld_sc4u(ux4& v, const void* p) {
  asm volatile("global_load_dwordx4 %0, %1, off sc0 sc1" : "=v"(v) : "v"(p) : "memory");
}
__device__ __forceinline__ void st_sc4(void* p, unsigned v) {
  asm volatile("global_store_dword %0, %1, off sc0 sc1" :: "v"(p), "v"(v) : "memory");
}

// ---------------- prep kernels ----------------

__global__ void k_convert(const float* __restrict__ src, ushort* __restrict__ dst, int n4) {
  int i = blockIdx.x * blockDim.x + threadIdx.x;
  int stride = gridDim.x * blockDim.x;
  for (; i < n4; i += stride) {
    float4 v = ((const float4*)src)[i];
    ((ushort4*)dst)[i] = make_ushort4(f2bf(v.x), f2bf(v.y), f2bf(v.z), f2bf(v.w));
  }
}

__global__ void k_bias(const float* __restrict__ bi, const float* __restrict__ bh,
                       float* __restrict__ bias) {
  int i = blockIdx.x * 256 + threadIdx.x;
  if (i < 4096) bias[i] = bi[i] + bh[i];
}

__global__ void k_gather(const int* __restrict__ tokens, const float* __restrict__ emb,
                         ushort* __restrict__ X) {
  int m = blockIdx.x * 4 + (threadIdx.x >> 6);
  int lane = threadIdx.x & 63;
  int b = m & 63, tt = m >> 6;
  int tok = tokens[b * 256 + tt];
  const float4* src = (const float4*)(emb + (size_t)tok * 512);
  ushort4* dst = (ushort4*)(X + (size_t)m * 512);
#pragma unroll
  for (int i = 0; i < 2; ++i) {
    float4 v = src[lane + i * 64];
    dst[lane + i * 64] = make_ushort4(f2bf(v.x), f2bf(v.y), f2bf(v.z), f2bf(v.w));
  }
}

// ---------------- K1: Xg = X @ W_ih^T + bias ----------------

__global__ __launch_bounds__(256) void k1_gemm(const ushort* __restrict__ X,
                                               const ushort* __restrict__ W,
                                               const float* __restrict__ bias,
                                               ushort* __restrict__ Xg) {
  __shared__ __align__(16) char As[128 * 128];
  __shared__ __align__(16) char Bs[128 * 128];
  const int tid = threadIdx.x, lane = tid & 63, wid = tid >> 6;
  const int wm = wid & 1, wn = wid >> 1;
  const int m0 = blockIdx.y * 128, n0 = blockIdx.x * 128;

  fx4 acc[4][4] = {};

  for (int kt = 0; kt < 8; ++kt) {
    if (kt) __syncthreads();
#pragma unroll
    for (int i = 0; i < 4; ++i) {
      int a = tid * 16 + i * 4096;
      int row = a >> 7, inrow = a & 127;
      int dsa = (row << 7) + (inrow ^ ((row & 7) << 4));
      sh8 va = *(const sh8*)((const char*)X + (size_t)(m0 + row) * 1024 + kt * 128 + inrow);
      *(sh8*)(As + dsa) = va;
      sh8 vb = *(const sh8*)((const char*)W + (size_t)(n0 + row) * 1024 + kt * 128 + inrow);
      *(sh8*)(Bs + dsa) = vb;
    }
    __syncthreads();
#pragma unroll
    for (int kb = 0; kb < 2; ++kb) {
      sh8 af[4], bf[4];
      const int ko = kb * 64 + ((lane >> 4) << 4);
#pragma unroll
      for (int x = 0; x < 4; ++x) {
        int ar = wm * 64 + x * 16 + (lane & 15);
        af[x] = *(const sh8*)(As + (ar << 7) + (ko ^ ((ar & 7) << 4)));
        int br = wn * 64 + x * 16 + (lane & 15);
        bf[x] = *(const sh8*)(Bs + (br << 7) + (ko ^ ((br & 7) << 4)));
      }
#pragma unroll
      for (int mi = 0; mi < 4; ++mi)
#pragma unroll
        for (int ni = 0; ni < 4; ++ni)
          acc[mi][ni] = __builtin_amdgcn_mfma_f32_16x16x32_bf16(af[mi], bf[ni], acc[mi][ni], 0, 0, 0);
    }
  }
#pragma unroll
  for (int ni = 0; ni < 4; ++ni) {
    int n = n0 + wn * 64 + ni * 16 + (lane & 15);
    float bv = bias[n];
#pragma unroll
    for (int mi = 0; mi < 4; ++mi) {
#pragma unroll
      for (int r = 0; r < 4; ++r) {
        int m = m0 + wm * 64 + mi * 16 + ((lane >> 4) << 2) + r;
        Xg[(size_t)m * 4096 + n] = f2bf(acc[mi][ni][r] + bv);
      }
    }
  }
}

// ---------------- K2: persistent LSTM recurrence ----------------
// Grid 256 = 64 hidx x 4 beta. WG: batches [beta*16,+16), units
// [hidx*16,+16). Wave wn == gate wn. h exchange: tagged dwords
// (bf16<<16 | t), 2 ping-pong slots of 256KB; staging loads double as
// the arrival poll.

__global__ __launch_bounds__(256, 1) void k2_lstm(const ushort* __restrict__ Whh,
                                                  const ushort* __restrict__ Xg,
                                                  const int* __restrict__ lengths,
                                                  unsigned* __restrict__ hbufT,
                                                  float* __restrict__ out) {
  __shared__ __align__(16) char hs[32768];   // 16 rows x 2048B bf16 (swizzled)
  __shared__ float gs[16][65];               // gates exchange

  const int tid = threadIdx.x, lane = tid & 63, wn = tid >> 6;
  const int wg = blockIdx.x;
  const int hidx = wg & 63, beta = wg >> 6;

  // ---- W_hh fragments (compiler keeps in regs or L1-hits reloads) ----
  const int grow = wn * 1024 + hidx * 16 + (lane & 15);  // gate row
  sh8 wf[32];
  {
    const char* wsrc = (const char*)Whh + (size_t)grow * 2048 + ((lane >> 4) << 4);
#pragma unroll
    for (int kb = 0; kb < 32; ++kb) {
      wf[kb] = *(const sh8*)(wsrc + (kb << 6));
      asm volatile("" : "+v"(wf[kb]));  // opaque def: discourage remat
    }
  }

  const int b_loc = tid >> 4, j16 = tid & 15;
  const int bglob = beta * 16 + b_loc;
  const int len = lengths[bglob];
  float h_s = 0.0f, c_s = 0.0f;

  // A-fragment LDS addressing (constant across steps)
  const int arow = lane & 15;
  const char* abase = hs + (arow << 11);
  const int asw = (arow & 7) << 4;
  const int ahi = (lane >> 4) << 4;

  // tagged exchange bases: slot s at hbufT + s*65536 dwords
  // consumer read region: rows beta*16..+16 -> dwords [beta*16384, +16384)
  const char* const stage0 = (const char*)hbufT + (size_t)beta * 65536 + tid * 16;
  const char* const stage1 = stage0 + 262144;
  // producer write target for h_{t+1}: unit (bglob*1024 + hidx*16 + j16)
  unsigned* const pub0 = hbufT + (size_t)bglob * 1024 + hidx * 16 + j16;
  unsigned* const pub1 = pub0 + 65536;

  // Xg for t=0 (prefetched; raw ushorts, converted at use)
  const ushort* x0 = Xg + (size_t)bglob * 4096 + hidx * 16 + j16;
  ushort xcu0 = x0[0], xcu1 = x0[1024], xcu2 = x0[2048], xcu3 = x0[3072];

  for (int t = 0; t < 256; ++t) {
    // ---- stage h (16 rows x 4KB tagged): poll-until-tag==t ----
    const char* sb = (t & 1) ? stage1 : stage0;
    const unsigned tag = (unsigned)t;
    ux4 L[16];
    for (;;) {
#pragma unroll
      for (int i = 0; i < 16; ++i) ld_sc4u(L[i], sb + i * 4096);
      asm volatile("s_waitcnt vmcnt(0)" ::: "memory");
      unsigned diff = 0;
#pragma unroll
      for (int i = 0; i < 16; ++i) {
        diff |= (L[i][0] ^ tag); diff |= (L[i][1] ^ tag);
        diff |= (L[i][2] ^ tag); diff |= (L[i][3] ^ tag);
      }
      if (__all((diff & 0xFFFFu) == 0u)) break;
    }
    // pack to bf16 and write LDS (swizzled); row i, bytes [tid*8, +8)
#pragma unroll
    for (int i = 0; i < 16; ++i) {
      ux2 p;
      p[0] = (L[i][0] >> 16) | (L[i][1] & 0xFFFF0000u);
      p[1] = (L[i][2] >> 16) | (L[i][3] & 0xFFFF0000u);
      *(ux2*)(hs + (i << 11) + ((tid * 8) ^ ((i & 7) << 4))) = p;
    }
    __syncthreads();

    // prefetch next step's Xg (plain loads; full-step latency window)
    const int tn = (t + 1) & 255;
    const ushort* xn = Xg + (size_t)tn * 262144 + (size_t)bglob * 4096 + hidx * 16 + j16;
    ushort nx0 = xn[0], nx1 = xn[1024], nx2 = xn[2048], nx3 = xn[3072];

    // ---- MFMA: 16 batches x 16 gate-cols, K=1024, 4 acc chains ----
    fx4 ac0 = {0,0,0,0}, ac1 = {0,0,0,0}, ac2 = {0,0,0,0}, ac3 = {0,0,0,0};
#pragma unroll
    for (int kb = 0; kb < 8; ++kb) {
      sh8 a0 = *(const sh8*)(abase + ((((4*kb+0) << 6) + ahi) ^ asw));
      ac0 = __builtin_amdgcn_mfma_f32_16x16x32_bf16(a0, wf[4*kb+0], ac0, 0, 0, 0);
      sh8 a1 = *(const sh8*)(abase + ((((4*kb+1) << 6) + ahi) ^ asw));
      ac1 = __builtin_amdgcn_mfma_f32_16x16x32_bf16(a1, wf[4*kb+1], ac1, 0, 0, 0);
      sh8 a2 = *(const sh8*)(abase + ((((4*kb+2) << 6) + ahi) ^ asw));
      ac2 = __builtin_amdgcn_mfma_f32_16x16x32_bf16(a2, wf[4*kb+2], ac2, 0, 0, 0);
      sh8 a3 = *(const sh8*)(abase + ((((4*kb+3) << 6) + ahi) ^ asw));
      ac3 = __builtin_amdgcn_mfma_f32_16x16x32_bf16(a3, wf[4*kb+3], ac3, 0, 0, 0);
    }
    fx4 acc = (ac0 + ac1) + (ac2 + ac3);

    // ---- gate exchange ----
    {
      const int gr = (lane >> 4) << 2;
      const int gc = wn * 16 + (lane & 15);
#pragma unroll
      for (int r = 0; r < 4; ++r) gs[gr + r][gc] = acc[r];
    }
    __syncthreads();

    // ---- pointwise LSTM cell ----
    {
      float gi = gs[b_loc][ 0 + j16] + bf2f(xcu0);
      float gf = gs[b_loc][16 + j16] + bf2f(xcu1);
      float gg = gs[b_loc][32 + j16] + bf2f(xcu2);
      float go = gs[b_loc][48 + j16] + bf2f(xcu3);
      if (t < len) {
        float iv = sigm(gi), fv = sigm(gf), gv = tanh_(gg), ov = sigm(go);
        c_s = fv * c_s + iv * gv;
        h_s = ov * tanh_(c_s);
      }
    }

    // ---- publish h_{t+1}: one tagged dword per thread, fire-and-forget ----
    {
      unsigned v = ((unsigned)f2bf(h_s) << 16) | (unsigned)(t + 1);
      st_sc4((t & 1) ? pub0 : pub1, v);  // slot (t+1)&1
    }

    xcu0 = nx0; xcu1 = nx1; xcu2 = nx2; xcu3 = nx3;
  }

  out[(size_t)bglob * 1024 + hidx * 16 + j16] = h_s;
}

// ---------------- launch ----------------

extern "C" void kernel_launch(void* const* d_in, const int* in_sizes, int n_in,
                              void* d_out, int out_size, void* d_ws, size_t ws_size,
                              hipStream_t stream) {
  (void)in_sizes; (void)n_in; (void)out_size;
  const int*   tokens  = (const int*)  d_in[0];
  const int*   lengths = (const int*)  d_in[1];
  const float* emb     = (const float*)d_in[2];
  const float* W_ih    = (const float*)d_in[3];
  const float* W_hh    = (const float*)d_in[4];
  const float* b_ih    = (const float*)d_in[5];
  const float* b_hh    = (const float*)d_in[6];
  float* out = (float*)d_out;
  char* ws = (char*)d_ws;

  const size_t off_X    = 0;                                    // 16 MiB
  const size_t off_Wih  = off_X    + (size_t)16384 * 512 * 2;   // 4 MiB
  const size_t off_Whh  = off_Wih  + (size_t)4096 * 512 * 2;    // 8 MiB
  const size_t off_bias = off_Whh  + (size_t)4096 * 1024 * 2;   // 16 KiB
  const size_t off_Xg   = off_bias + (size_t)4096 * 4;          // 128 MiB
  const size_t off_hbT  = off_Xg   + (size_t)16384 * 4096 * 2;  // 512 KiB (2 tagged slots)
  const size_t need     = off_hbT + (size_t)2 * 64 * 1024 * 4;
  if (ws_size < need) return;

  ushort*   Xb    = (ushort*)(ws + off_X);
  ushort*   Wih_b = (ushort*)(ws + off_Wih);
  ushort*   Whh_b = (ushort*)(ws + off_Whh);
  float*    bias  = (float*) (ws + off_bias);
  ushort*   Xg    = (ushort*)(ws + off_Xg);
  unsigned* hbT   = (unsigned*)(ws + off_hbT);

  hipMemsetAsync(ws + off_hbT, 0, (size_t)2 * 64 * 1024 * 4, stream);  // h0=0, tag 0
  k_convert<<<1024, 256, 0, stream>>>(W_ih, Wih_b, 4096 * 512 / 4);
  k_convert<<<1024, 256, 0, stream>>>(W_hh, Whh_b, 4096 * 1024 / 4);
  k_bias<<<16, 256, 0, stream>>>(b_ih, b_hh, bias);
  k_gather<<<4096, 256, 0, stream>>>(tokens, emb, Xb);
  k1_gemm<<<dim3(32, 128), 256, 0, stream>>>(Xb, Wih_b, bias, Xg);
  k2_lstm<<<256, 256, 0, stream>>>(Whh_b, Xg, lengths, hbT, out);
}